// Round 1
// baseline (623.746 us; speedup 1.0000x reference)
//
#include <hip/hip_runtime.h>

#define U_N 100000
#define I_N 50000
#define KD 64
#define NI 2000000
#define BB 4096
#define SLOPE 0.01f

// ---------------- kernels ----------------

__global__ __launch_bounds__(256) void k_build_map(const int* __restrict__ users,
                                                   int* __restrict__ map) {
    int b = blockIdx.x * 256 + threadIdx.x;
    if (b < BB) atomicMin(&map[users[b]], b);
}

// rows [0, I_N): PI[r] = Gi[r] @ W1iT          (no bias)
// rows [I_N, I_N+BB): PUB[b] = Gu[users[b]] @ W1uT + b1   (representatives only)
__global__ __launch_bounds__(256) void k_precompute(const float* __restrict__ Gu,
                                                    const float* __restrict__ Gi,
                                                    const float* __restrict__ W1,
                                                    const float* __restrict__ b1,
                                                    const int* __restrict__ users,
                                                    const int* __restrict__ map,
                                                    float* __restrict__ PI,
                                                    float* __restrict__ PUB) {
    __shared__ float w1t[128 * 64];  // w1t[k*64+j] = W1[j*128+k]
    for (int idx = threadIdx.x; idx < 128 * 64; idx += 256) {
        int j = idx >> 7, k = idx & 127;
        w1t[k * 64 + j] = W1[idx];
    }
    __syncthreads();
    int lane = threadIdx.x & 63;
    int r = blockIdx.x * 4 + (threadIdx.x >> 6);
    if (r >= I_N + BB) return;

    const float* row;
    const float* wpart;
    float acc;
    float* outp;
    if (r < I_N) {
        row = Gi + (size_t)r * KD;
        wpart = w1t + 64 * 64;  // k in [64,128) half
        acc = 0.0f;
        outp = PI + (size_t)r * KD;
    } else {
        int b = r - I_N;
        int u = users[b];
        if (map[u] != b) return;  // not the representative slot for this user
        row = Gu + (size_t)u * KD;
        wpart = w1t;              // k in [0,64) half
        acc = b1[lane];
        outp = PUB + (size_t)b * KD;
    }
    float g = row[lane];
#pragma unroll
    for (int k = 0; k < 64; ++k) {
        acc += __shfl(g, k) * wpart[k * 64 + lane];
    }
    outp[lane] = acc;
}

// one thread per interaction: compact flagged interactions, count per slot
__global__ __launch_bounds__(256) void k_filter(const int* __restrict__ ui_u,
                                                const int* __restrict__ map,
                                                int* __restrict__ list,
                                                int* __restrict__ listCount,
                                                int* __restrict__ counts) {
    int t = blockIdx.x * 256 + threadIdx.x;
    if (t >= NI) return;
    int rep = map[ui_u[t]];
    if (rep < BB) {
        int pos = atomicAdd(listCount, 1);
        list[pos] = t;
        atomicAdd(&counts[rep], 1);
    }
}

// one wave per flagged interaction (grid-stride): sums[rep] += lrelu(PUB[rep] + PI[item])
__global__ __launch_bounds__(256) void k_accum(const int* __restrict__ ui_u,
                                               const int* __restrict__ ui_i,
                                               const int* __restrict__ map,
                                               const int* __restrict__ list,
                                               const int* __restrict__ listCount,
                                               const float* __restrict__ PUB,
                                               const float* __restrict__ PI,
                                               float* __restrict__ sums) {
    int lane = threadIdx.x & 63;
    int wave = (blockIdx.x * 256 + threadIdx.x) >> 6;
    int nwaves = (gridDim.x * 256) >> 6;
    int n = *listCount;
    for (int e = wave; e < n; e += nwaves) {
        int t = list[e];
        int rep = map[ui_u[t]];
        int it = ui_i[t];
        float v = PUB[(size_t)rep * KD + lane] + PI[(size_t)it * KD + lane];
        v = (v > 0.0f) ? v : v * SLOPE;
        atomicAdd(&sums[(size_t)rep * KD + lane], v);
    }
}

// one wave per batch element: both matvecs vs W2, dot product, gamma_i copy
__global__ __launch_bounds__(256) void k_final(const int* __restrict__ users,
                                               const int* __restrict__ items,
                                               const int* __restrict__ map,
                                               const float* __restrict__ sums,
                                               const int* __restrict__ counts,
                                               const float* __restrict__ PUB,
                                               const float* __restrict__ PI,
                                               const float* __restrict__ W2,
                                               const float* __restrict__ b2,
                                               const float* __restrict__ Gi,
                                               float* __restrict__ out) {
    __shared__ float w2t[64 * 64];  // w2t[k*64+j] = W2[j*64+k]
    for (int idx = threadIdx.x; idx < 64 * 64; idx += 256) {
        int j = idx >> 6, k = idx & 63;
        w2t[k * 64 + j] = W2[idx];
    }
    __syncthreads();
    int lane = threadIdx.x & 63;
    int b = blockIdx.x * 4 + (threadIdx.x >> 6);
    if (b >= BB) return;

    int u = users[b];
    int rep = map[u];
    int it = items[b];
    int c = counts[rep];
    if (c < 1) c = 1;
    float inv = 1.0f / (float)c;

    float A = sums[(size_t)rep * KD + lane] * inv;            // mean of lrelu, elem `lane`
    float av = PUB[(size_t)rep * KD + lane] + PI[(size_t)it * KD + lane];
    av = (av > 0.0f) ? av : av * SLOPE;                       // lrelu for gui path

    float gu = b2[lane];
    float gi = b2[lane];
#pragma unroll
    for (int k = 0; k < 64; ++k) {
        float w = w2t[k * 64 + lane];
        gu += __shfl(A, k) * w;
        gi += __shfl(av, k) * w;
    }

    float prod = gu * gi;
#pragma unroll
    for (int off = 32; off > 0; off >>= 1) prod += __shfl_down(prod, off);

    if (lane == 0) out[b] = prod;                             // xui
    out[(size_t)BB + (size_t)b * KD + lane] = gu;             // gu_star
    out[(size_t)BB + (size_t)BB * KD + (size_t)b * KD + lane] =
        Gi[(size_t)it * KD + lane];                           // gamma_i
}

// ---------------- launch ----------------

extern "C" void kernel_launch(void* const* d_in, const int* in_sizes, int n_in,
                              void* d_out, int out_size, void* d_ws, size_t ws_size,
                              hipStream_t stream) {
    const float* Gu = (const float*)d_in[0];
    const float* Gi = (const float*)d_in[1];
    const float* W1 = (const float*)d_in[2];
    const float* b1 = (const float*)d_in[3];
    const float* W2 = (const float*)d_in[4];
    const float* b2 = (const float*)d_in[5];
    const int* users = (const int*)d_in[6];
    const int* items = (const int*)d_in[7];
    const int* ui = (const int*)d_in[8];
    const int* ui_u = ui;            // row 0
    const int* ui_i = ui + NI;       // row 1
    float* out = (float*)d_out;

    char* ws = (char*)d_ws;
    size_t off = 0;
    int* map = (int*)(ws + off);       off += 400128;       // 100000*4 padded
    float* PI = (float*)(ws + off);    off += 12800000;     // 50000*64*4
    float* PUB = (float*)(ws + off);   off += 1048576;      // 4096*64*4
    float* sums = (float*)(ws + off);  off += 1048576;      // 4096*64*4
    int* counts = (int*)(ws + off);    off += 16384;        // 4096*4
    int* listCount = (int*)(ws + off); off += 128;
    int* list = (int*)(ws + off);      off += 8000000;      // 2000000*4 worst case

    // reset per-call state (captured in graph => replayed each call)
    hipMemsetAsync(map, 0x7f, (size_t)U_N * 4, stream);      // 0x7f7f7f7f > any batch idx
    hipMemsetAsync(sums, 0, (size_t)BB * KD * 4, stream);
    hipMemsetAsync(counts, 0, (size_t)BB * 4, stream);
    hipMemsetAsync(listCount, 0, 4, stream);

    k_build_map<<<(BB + 255) / 256, 256, 0, stream>>>(users, map);

    int rows = I_N + BB;
    k_precompute<<<(rows + 3) / 4, 256, 0, stream>>>(Gu, Gi, W1, b1, users, map, PI, PUB);

    k_filter<<<(NI + 255) / 256, 256, 0, stream>>>(ui_u, map, list, listCount, counts);

    k_accum<<<2048, 256, 0, stream>>>(ui_u, ui_i, map, list, listCount, PUB, PI, sums);

    k_final<<<BB / 4, 256, 0, stream>>>(users, items, map, sums, counts, PUB, PI, W2, b2, Gi, out);
}

// Round 2
// 144.827 us; speedup vs baseline: 4.3068x; 4.3068x over previous
//
#include <hip/hip_runtime.h>

#define U_N 100000
#define I_N 50000
#define KD 64
#define NI 2000000
#define BB 4096
#define SLOPE 0.01f
#define CHUNK 2048

// ---------------- kernels ----------------

__global__ __launch_bounds__(256) void k_build_map(const int* __restrict__ users,
                                                   int* __restrict__ map) {
    int b = blockIdx.x * 256 + threadIdx.x;
    if (b < BB) atomicMin(&map[users[b]], b);
}

// rows [0, I_N): PI[r] = Gi[r] @ W1iT          (no bias)
// rows [I_N, I_N+BB): PUB[b] = Gu[users[b]] @ W1uT + b1   (representatives only)
// 64 rows per block to amortize the W1 LDS staging.
__global__ __launch_bounds__(256) void k_precompute(const float* __restrict__ Gu,
                                                    const float* __restrict__ Gi,
                                                    const float* __restrict__ W1,
                                                    const float* __restrict__ b1,
                                                    const int* __restrict__ users,
                                                    const int* __restrict__ map,
                                                    float* __restrict__ PI,
                                                    float* __restrict__ PUB) {
    __shared__ float w1t[128 * 64];  // w1t[k*64+j] = W1[j*128+k]
    for (int idx = threadIdx.x; idx < 128 * 64; idx += 256) {
        int j = idx >> 7, k = idx & 127;
        w1t[k * 64 + j] = W1[idx];
    }
    __syncthreads();
    int lane = threadIdx.x & 63;
    int w = threadIdx.x >> 6;
    int base = blockIdx.x * 64;

    for (int rr = w; rr < 64; rr += 4) {
        int r = base + rr;
        if (r >= I_N + BB) break;

        const float* row;
        const float* wpart;
        float acc;
        float* outp;
        if (r < I_N) {
            row = Gi + (size_t)r * KD;
            wpart = w1t + 64 * 64;  // item half: k in [64,128)
            acc = 0.0f;
            outp = PI + (size_t)r * KD;
        } else {
            int b = r - I_N;
            int u = users[b];
            if (map[u] != b) continue;  // not the representative slot
            row = Gu + (size_t)u * KD;
            wpart = w1t;                // user half: k in [0,64)
            acc = b1[lane];
            outp = PUB + (size_t)b * KD;
        }
        float g = row[lane];
#pragma unroll
        for (int k = 0; k < 64; ++k) {
            acc += __shfl(g, k) * wpart[k * 64 + lane];
        }
        outp[lane] = acc;
    }
}

// fused filter + accumulate: per-block LDS compaction (no global list),
// then 4 waves cooperatively accumulate lrelu(PUB[rep] + PI[item]) into sums.
__global__ __launch_bounds__(256) void k_accum(const int* __restrict__ ui_u,
                                               const int* __restrict__ ui_i,
                                               const int* __restrict__ map,
                                               const float* __restrict__ PUB,
                                               const float* __restrict__ PI,
                                               float* __restrict__ sums,
                                               int* __restrict__ counts) {
    __shared__ int s_cnt;
    __shared__ int s_rep[CHUNK];
    __shared__ int s_item[CHUNK];
    if (threadIdx.x == 0) s_cnt = 0;
    __syncthreads();

    int base = blockIdx.x * CHUNK;
#pragma unroll
    for (int k = 0; k < CHUNK / 256; ++k) {
        int t = base + k * 256 + threadIdx.x;
        if (t < NI) {
            int rep = map[ui_u[t]];
            if (rep < BB) {
                int pos = atomicAdd(&s_cnt, 1);  // LDS atomic — per-block, cheap
                s_rep[pos] = rep;
                s_item[pos] = ui_i[t];
                atomicAdd(&counts[rep], 1);      // 82K atomics / 4096 addrs
            }
        }
    }
    __syncthreads();

    int n = s_cnt;
    int lane = threadIdx.x & 63;
    int w = threadIdx.x >> 6;
    for (int e = w; e < n; e += 4) {
        int rep = s_rep[e];
        int it = s_item[e];
        float v = PUB[rep * KD + lane] + PI[(size_t)it * KD + lane];
        v = (v > 0.0f) ? v : v * SLOPE;
        atomicAdd(&sums[rep * KD + lane], v);
    }
}

// one wave per batch element: both matvecs vs W2, dot product, gamma_i copy
__global__ __launch_bounds__(256) void k_final(const int* __restrict__ users,
                                               const int* __restrict__ items,
                                               const int* __restrict__ map,
                                               const float* __restrict__ sums,
                                               const int* __restrict__ counts,
                                               const float* __restrict__ PUB,
                                               const float* __restrict__ PI,
                                               const float* __restrict__ W2,
                                               const float* __restrict__ b2,
                                               const float* __restrict__ Gi,
                                               float* __restrict__ out) {
    __shared__ float w2t[64 * 64];  // w2t[k*64+j] = W2[j*64+k]
    for (int idx = threadIdx.x; idx < 64 * 64; idx += 256) {
        int j = idx >> 6, k = idx & 63;
        w2t[k * 64 + j] = W2[idx];
    }
    __syncthreads();
    int lane = threadIdx.x & 63;
    int b = blockIdx.x * 4 + (threadIdx.x >> 6);
    if (b >= BB) return;

    int u = users[b];
    int rep = map[u];
    int it = items[b];
    int c = counts[rep];
    if (c < 1) c = 1;
    float inv = 1.0f / (float)c;

    float A = sums[(size_t)rep * KD + lane] * inv;            // mean of lrelu
    float av = PUB[(size_t)rep * KD + lane] + PI[(size_t)it * KD + lane];
    av = (av > 0.0f) ? av : av * SLOPE;                       // lrelu for gui path

    float gu = b2[lane];
    float gi = b2[lane];
#pragma unroll
    for (int k = 0; k < 64; ++k) {
        float w = w2t[k * 64 + lane];
        gu += __shfl(A, k) * w;
        gi += __shfl(av, k) * w;
    }

    float prod = gu * gi;
#pragma unroll
    for (int off = 32; off > 0; off >>= 1) prod += __shfl_down(prod, off);

    if (lane == 0) out[b] = prod;                             // xui
    out[(size_t)BB + (size_t)b * KD + lane] = gu;             // gu_star
    out[(size_t)BB + (size_t)BB * KD + (size_t)b * KD + lane] =
        Gi[(size_t)it * KD + lane];                           // gamma_i
}

// ---------------- launch ----------------

extern "C" void kernel_launch(void* const* d_in, const int* in_sizes, int n_in,
                              void* d_out, int out_size, void* d_ws, size_t ws_size,
                              hipStream_t stream) {
    const float* Gu = (const float*)d_in[0];
    const float* Gi = (const float*)d_in[1];
    const float* W1 = (const float*)d_in[2];
    const float* b1 = (const float*)d_in[3];
    const float* W2 = (const float*)d_in[4];
    const float* b2 = (const float*)d_in[5];
    const int* users = (const int*)d_in[6];
    const int* items = (const int*)d_in[7];
    const int* ui = (const int*)d_in[8];
    const int* ui_u = ui;            // row 0
    const int* ui_i = ui + NI;       // row 1
    float* out = (float*)d_out;

    char* ws = (char*)d_ws;
    size_t off = 0;
    int* map = (int*)(ws + off);       off += 400128;       // 100000*4 padded
    float* PI = (float*)(ws + off);    off += 12800000;     // 50000*64*4
    float* PUB = (float*)(ws + off);   off += 1048576;      // 4096*64*4
    float* sums = (float*)(ws + off);  off += 1048576;      // 4096*64*4
    int* counts = (int*)(ws + off);    off += 16384;        // 4096*4

    hipMemsetAsync(map, 0x7f, (size_t)U_N * 4, stream);      // 0x7f7f7f7f > any slot
    hipMemsetAsync(sums, 0, (size_t)BB * KD * 4, stream);
    hipMemsetAsync(counts, 0, (size_t)BB * 4, stream);

    k_build_map<<<(BB + 255) / 256, 256, 0, stream>>>(users, map);

    int rows = I_N + BB;
    k_precompute<<<(rows + 63) / 64, 256, 0, stream>>>(Gu, Gi, W1, b1, users, map, PI, PUB);

    k_accum<<<(NI + CHUNK - 1) / CHUNK, 256, 0, stream>>>(ui_u, ui_i, map, PUB, PI, sums, counts);

    k_final<<<BB / 4, 256, 0, stream>>>(users, items, map, sums, counts, PUB, PI, W2, b2, Gi, out);
}

// Round 3
// 97.367 us; speedup vs baseline: 6.4061x; 1.4874x over previous
//
#include <hip/hip_runtime.h>

#define U_N 100000
#define I_N 50000
#define KD 64
#define NI 2000000
#define BB 4096
#define SLOPE 0.01f
#define CHUNK 2048
#define PI_BLOCKS 782  // ceil(50000/64)

// ---------------- kernels ----------------

__global__ __launch_bounds__(256) void k_build_map(const int* __restrict__ users,
                                                   int* __restrict__ map) {
    int b = blockIdx.x * 256 + threadIdx.x;
    if (b < BB) atomicMin(&map[users[b]], b);
}

// Register-tiled fp32 GEMM: [rows x 64] @ [64 x 64]^T-free (dot-product form).
// Blocks [0, PI_BLOCKS): PI[r] = Gi[r] . W1[:, 64:128]   (item half, no bias)
// Blocks [PI_BLOCKS, +64): PUB[b] = Gu[users[b]] . W1[:, 0:64] + b1  (all slots)
// Both LDS tiles in [row][k] layout, float4-group XOR swizzle (g ^= row>>2).
__global__ __launch_bounds__(256) void k_precompute(const float* __restrict__ Gu,
                                                    const float* __restrict__ Gi,
                                                    const float* __restrict__ W1,
                                                    const float* __restrict__ b1,
                                                    const int* __restrict__ users,
                                                    float* __restrict__ PI,
                                                    float* __restrict__ PUB) {
    __shared__ float4 wt[64 * 16];  // wt[c*16 + (g ^ (c>>2))] = W1[c][off + 4g .. +3]
    __shared__ float4 at[64 * 16];  // at[r*16 + (g ^ (r>>2))] = row[r][4g .. +3]
    const int tid = threadIdx.x;
    const bool isPUB = (blockIdx.x >= PI_BLOCKS);
    const int base = isPUB ? (int)(blockIdx.x - PI_BLOCKS) * 64 : (int)blockIdx.x * 64;
    const int off = isPUB ? 0 : KD;  // W1 input-half: user [0,64), item [64,128)

    for (int fidx = tid; fidx < 1024; fidx += 256) {
        int c = fidx >> 4, g = fidx & 15;
        wt[c * 16 + (g ^ (c >> 2))] = *(const float4*)(W1 + c * 128 + off + g * 4);
    }
    for (int fidx = tid; fidx < 1024; fidx += 256) {
        int lr = fidx >> 4, g = fidx & 15;
        int r = base + lr;
        const float* src = isPUB ? (Gu + (size_t)users[r] * KD)
                                 : (Gi + (size_t)(r < I_N ? r : I_N - 1) * KD);
        at[lr * 16 + (g ^ (lr >> 2))] = *(const float4*)(src + g * 4);
    }
    __syncthreads();

    const int ty = tid >> 4, tx = tid & 15;  // rows ty*4..+3, cols tx*4..+3
    float acc[4][4];
    if (isPUB) {
        float4 bv = *(const float4*)(b1 + tx * 4);
#pragma unroll
        for (int i = 0; i < 4; ++i) {
            acc[i][0] = bv.x; acc[i][1] = bv.y; acc[i][2] = bv.z; acc[i][3] = bv.w;
        }
    } else {
#pragma unroll
        for (int i = 0; i < 4; ++i)
            for (int j = 0; j < 4; ++j) acc[i][j] = 0.0f;
    }

#pragma unroll
    for (int g = 0; g < 16; ++g) {
        float4 a[4], w[4];
#pragma unroll
        for (int i = 0; i < 4; ++i) a[i] = at[(ty * 4 + i) * 16 + (g ^ ty)];
#pragma unroll
        for (int j = 0; j < 4; ++j) w[j] = wt[(tx * 4 + j) * 16 + (g ^ tx)];
#pragma unroll
        for (int i = 0; i < 4; ++i)
#pragma unroll
            for (int j = 0; j < 4; ++j)
                acc[i][j] += a[i].x * w[j].x + a[i].y * w[j].y +
                             a[i].z * w[j].z + a[i].w * w[j].w;
    }

    float* outp = isPUB ? PUB : PI;
#pragma unroll
    for (int i = 0; i < 4; ++i) {
        int r = base + ty * 4 + i;
        if (!isPUB && r >= I_N) continue;
        float4 v = {acc[i][0], acc[i][1], acc[i][2], acc[i][3]};
        *(float4*)(outp + (size_t)r * KD + tx * 4) = v;
    }
}

// fused filter + accumulate: per-block LDS compaction (no global list),
// then 4 waves cooperatively accumulate lrelu(PUB[rep] + PI[item]) into sums.
__global__ __launch_bounds__(256) void k_accum(const int* __restrict__ ui_u,
                                               const int* __restrict__ ui_i,
                                               const int* __restrict__ map,
                                               const float* __restrict__ PUB,
                                               const float* __restrict__ PI,
                                               float* __restrict__ sums,
                                               int* __restrict__ counts) {
    __shared__ int s_cnt;
    __shared__ int s_rep[CHUNK];
    __shared__ int s_item[CHUNK];
    if (threadIdx.x == 0) s_cnt = 0;
    __syncthreads();

    int base = blockIdx.x * CHUNK;
#pragma unroll
    for (int k = 0; k < CHUNK / 256; ++k) {
        int t = base + k * 256 + threadIdx.x;
        if (t < NI) {
            int rep = map[ui_u[t]];
            if (rep < BB) {
                int pos = atomicAdd(&s_cnt, 1);  // LDS atomic — per-block, cheap
                s_rep[pos] = rep;
                s_item[pos] = ui_i[t];
                atomicAdd(&counts[rep], 1);
            }
        }
    }
    __syncthreads();

    int n = s_cnt;
    int lane = threadIdx.x & 63;
    int w = threadIdx.x >> 6;
    for (int e = w; e < n; e += 4) {
        int rep = s_rep[e];
        int it = s_item[e];
        float v = PUB[rep * KD + lane] + PI[(size_t)it * KD + lane];
        v = (v > 0.0f) ? v : v * SLOPE;
        atomicAdd(&sums[rep * KD + lane], v);
    }
}

// one wave per batch element: both matvecs vs W2, dot product, gamma_i copy
__global__ __launch_bounds__(256) void k_final(const int* __restrict__ users,
                                               const int* __restrict__ items,
                                               const int* __restrict__ map,
                                               const float* __restrict__ sums,
                                               const int* __restrict__ counts,
                                               const float* __restrict__ PUB,
                                               const float* __restrict__ PI,
                                               const float* __restrict__ W2,
                                               const float* __restrict__ b2,
                                               const float* __restrict__ Gi,
                                               float* __restrict__ out) {
    __shared__ float w2t[64 * 64];  // w2t[k*64+j] = W2[j*64+k]
    for (int idx = threadIdx.x; idx < 64 * 64; idx += 256) {
        int j = idx >> 6, k = idx & 63;
        w2t[k * 64 + j] = W2[idx];
    }
    __syncthreads();
    int lane = threadIdx.x & 63;
    int b = blockIdx.x * 4 + (threadIdx.x >> 6);
    if (b >= BB) return;

    int u = users[b];
    int rep = map[u];
    int it = items[b];
    int c = counts[rep];
    if (c < 1) c = 1;
    float inv = 1.0f / (float)c;

    float A = sums[(size_t)rep * KD + lane] * inv;            // mean of lrelu
    float av = PUB[(size_t)rep * KD + lane] + PI[(size_t)it * KD + lane];
    av = (av > 0.0f) ? av : av * SLOPE;                       // lrelu for gui path

    float gu = b2[lane];
    float gi = b2[lane];
#pragma unroll
    for (int k = 0; k < 64; ++k) {
        float w = w2t[k * 64 + lane];
        gu += __shfl(A, k) * w;
        gi += __shfl(av, k) * w;
    }

    float prod = gu * gi;
#pragma unroll
    for (int off = 32; off > 0; off >>= 1) prod += __shfl_down(prod, off);

    if (lane == 0) out[b] = prod;                             // xui
    out[(size_t)BB + (size_t)b * KD + lane] = gu;             // gu_star
    out[(size_t)BB + (size_t)BB * KD + (size_t)b * KD + lane] =
        Gi[(size_t)it * KD + lane];                           // gamma_i
}

// ---------------- launch ----------------

extern "C" void kernel_launch(void* const* d_in, const int* in_sizes, int n_in,
                              void* d_out, int out_size, void* d_ws, size_t ws_size,
                              hipStream_t stream) {
    const float* Gu = (const float*)d_in[0];
    const float* Gi = (const float*)d_in[1];
    const float* W1 = (const float*)d_in[2];
    const float* b1 = (const float*)d_in[3];
    const float* W2 = (const float*)d_in[4];
    const float* b2 = (const float*)d_in[5];
    const int* users = (const int*)d_in[6];
    const int* items = (const int*)d_in[7];
    const int* ui = (const int*)d_in[8];
    const int* ui_u = ui;            // row 0
    const int* ui_i = ui + NI;       // row 1
    float* out = (float*)d_out;

    char* ws = (char*)d_ws;
    size_t off = 0;
    int* map = (int*)(ws + off);       off += 400128;       // 100000*4 padded
    float* PI = (float*)(ws + off);    off += 12800000;     // 50000*64*4
    float* PUB = (float*)(ws + off);   off += 1048576;      // 4096*64*4
    float* sums = (float*)(ws + off);  off += 1048576;      // 4096*64*4
    int* counts = (int*)(ws + off);    off += 16384;        // 4096*4

    hipMemsetAsync(map, 0x7f, (size_t)U_N * 4, stream);      // 0x7f7f7f7f > any slot
    hipMemsetAsync(sums, 0, (size_t)BB * KD * 4, stream);
    hipMemsetAsync(counts, 0, (size_t)BB * 4, stream);

    k_build_map<<<(BB + 255) / 256, 256, 0, stream>>>(users, map);

    k_precompute<<<PI_BLOCKS + BB / 64, 256, 0, stream>>>(Gu, Gi, W1, b1, users, PI, PUB);

    k_accum<<<(NI + CHUNK - 1) / CHUNK, 256, 0, stream>>>(ui_u, ui_i, map, PUB, PI, sums, counts);

    k_final<<<BB / 4, 256, 0, stream>>>(users, items, map, sums, counts, PUB, PI, W2, b2, Gi, out);
}